// Round 2
// baseline (484.934 us; speedup 1.0000x reference)
//
#include <hip/hip_runtime.h>

#define N_NODES   50000
#define N_EDGES   800000
#define DF        64          // feature dim (D_IN == D_HID == 64)
#define N_GRAPHS  64
#define NPAD      50176       // 98*512, padded node count

// ---- two-level counting-sort CSR build (no global atomics, no write amp) ----
#define ABLK 200              // binning blocks
#define AEDG (N_EDGES/ABLK)   // 4000 edges per block
#define RSH  9                // 512 nodes per region
#define NREG 98               // 98*512 = 50176 >= N_NODES
#define RPAD 128              // padded region count
#define CAP  12288            // LDS esrc image capacity per region (avg 8163)

// Pass A1: per-block region histogram -> H transposed [region][block]
// Block 0 also zeroes the pool buffer.
__global__ __launch_bounds__(256)
void k_hist(const int* __restrict__ col, int* __restrict__ H,
            float* __restrict__ pool) {
    __shared__ int h[RPAD];
    const int t = threadIdx.x, b = blockIdx.x;
    if (b == 0)
        for (int i = t; i < N_GRAPHS * DF; i += 256) pool[i] = 0.f;
    if (t < RPAD) h[t] = 0;
    __syncthreads();
    const int e0 = b * AEDG;
    for (int i = t; i < AEDG; i += 256)
        atomicAdd(&h[col[e0 + i] >> RSH], 1);
    __syncthreads();
    if (t < RPAD) H[t * ABLK + b] = h[t];
}

// Pass A2: one block PER REGION: exclusive scan of H[r][0..199] -> O, total -> T
__global__ __launch_bounds__(256)
void k_scanH(const int* __restrict__ H, int* __restrict__ O,
             int* __restrict__ T) {
    __shared__ int s[256];
    const int t = threadIdx.x, r = blockIdx.x;
    int v = (t < ABLK) ? H[r * ABLK + t] : 0;
    s[t] = v; __syncthreads();
    #pragma unroll
    for (int off = 1; off < 256; off <<= 1) {
        int x = (t >= off) ? s[t - off] : 0;
        __syncthreads();
        s[t] += x;
        __syncthreads();
    }
    if (t < ABLK) O[r * ABLK + t] = s[t] - v;   // exclusive, region-local
    if (t == 255) T[r] = s[255];
}

// Pass A3: scatter packed edges into region-sorted staging (block-local runs).
__global__ __launch_bounds__(256)
void k_bin(const int* __restrict__ row, const int* __restrict__ col,
           const int* __restrict__ O, const int* __restrict__ T,
           unsigned* __restrict__ staging) {
    __shared__ int cur[RPAD];
    __shared__ int rs[RPAD];
    const int t = threadIdx.x, b = blockIdx.x;
    int v = 0;
    if (t < RPAD) { v = T[t]; rs[t] = v; }
    __syncthreads();
    #pragma unroll
    for (int off = 1; off < RPAD; off <<= 1) {
        int x = 0;
        if (t < RPAD && t >= off) x = rs[t - off];
        __syncthreads();
        if (t < RPAD) rs[t] += x;
        __syncthreads();
    }
    if (t < RPAD) cur[t] = O[t * ABLK + b] + (rs[t] - v);   // + R[t]
    __syncthreads();
    const int e0 = b * AEDG;
    for (int i = t; i < AEDG; i += 256) {
        int c = col[e0 + i];
        int rr = row[e0 + i];
        int slot = atomicAdd(&cur[c >> RSH], 1);      // LDS atomic
        staging[slot] = ((unsigned)c << 16) | (unsigned)rr;
    }
}

// Pass B: one block per region -> offs, dinv, epack (all coalesced writes)
// R1 change: epack[e] = src | (local_target << 16)  (src<65536, ln<512) so the
// streaming gather can resolve the accumulation target WITHOUT walking offs.
__global__ __launch_bounds__(512)
void k_csr(const unsigned* __restrict__ staging, const int* __restrict__ T,
           int* __restrict__ offs, float* __restrict__ dinv,
           unsigned* __restrict__ epack) {
    __shared__ int hist[512];
    __shared__ int cur[512];
    __shared__ unsigned img[CAP];
    __shared__ int rs[RPAD];
    __shared__ int sh_s0, sh_s1;
    const int t = threadIdx.x, r = blockIdx.x;
    int v = 0;
    if (t < RPAD) { v = T[t]; rs[t] = v; }
    __syncthreads();
    #pragma unroll
    for (int off = 1; off < RPAD; off <<= 1) {
        int x = 0;
        if (t < RPAD && t >= off) x = rs[t - off];
        __syncthreads();
        if (t < RPAD) rs[t] += x;
        __syncthreads();
    }
    if (t == r) { sh_s0 = rs[t] - v; sh_s1 = rs[t]; }
    hist[t] = 0;
    __syncthreads();
    const int s0 = sh_s0, s1 = sh_s1;
    for (int i = s0 + t; i < s1; i += 512) {
        int ln = (int)(staging[i] >> 16) - (r << RSH);
        atomicAdd(&hist[ln], 1);
    }
    __syncthreads();
    int myc = hist[t];
    #pragma unroll
    for (int off = 1; off < 512; off <<= 1) {         // inclusive scan
        int x = (t >= off) ? hist[t - off] : 0;
        __syncthreads();
        hist[t] += x;
        __syncthreads();
    }
    int excl = hist[t] - myc;
    int n = (r << RSH) + t;
    offs[n] = s0 + excl;                               // incl. sentinel nodes
    if (n < N_NODES) dinv[n] = rsqrtf((float)(myc + 1));
    cur[t] = excl;
    __syncthreads();
    for (int i = s0 + t; i < s1; i += 512) {
        unsigned p = staging[i];
        int ln = (int)(p >> 16) - (r << RSH);
        unsigned rr = p & 0xFFFFu;
        unsigned pk = rr | ((unsigned)ln << 16);       // src + local target
        int slot = atomicAdd(&cur[ln], 1);             // LDS atomic
        if (slot < CAP) img[slot] = pk;
        else           epack[s0 + slot] = pk;          // overflow fallback
    }
    __syncthreads();
    int cnt = s1 - s0; if (cnt > CAP) cnt = CAP;
    for (int j = t; j < cnt; j += 512) epack[s0 + j] = img[j];
}

// ---------------- fused edge-streaming gather + GEMM (+ pool epilogue) -------
// R1: gather is restructured from node-walks (3 dependent round trips per
// node: offs->esrc->dinv/h) to EDGE STREAMING: the block's 64 nodes own a
// contiguous span of the target-sorted edge list; 8 waves stream equal
// slices. epack+dinv[src] are sequential-prefetchable; the only dependent
// hop is epack -> h-row (chain depth 1). Per-lane run detection on the
// sorted target accumulates in registers; flushes go through LDS float
// atomics into node-major Xacc[64][65] (stride 65 => <=2-way banks on both
// the atomic flush and the GEMM b32 reads). dinv[tgt] scaling deferred to
// flush (linear). Self-loops pre-initialize Xacc with plain stores.
#define FB_ROWS 64
#define LDA 65

__global__ __launch_bounds__(512, 4)
void k_fused(const int* __restrict__ offs, const unsigned* __restrict__ epack,
             const float* __restrict__ dinv, const float* __restrict__ h,
             const float* __restrict__ W, const float* __restrict__ bias,
             float* __restrict__ out, const int* __restrict__ batch,
             float* __restrict__ pool) {
    __shared__ float Xacc[FB_ROWS][LDA];   // 16.6 KB, node-major agg tile
    __shared__ float Ws[DF][DF];           // 16 KB
    __shared__ float sh_dinv[FB_ROWS];
    __shared__ float plocal[4 * DF];       // block-local pool partials
    __shared__ int   sh_batch[FB_ROWS];
    __shared__ int   sh_e0, sh_e1;

    const int t = threadIdx.x;
    const int row0 = blockIdx.x * FB_ROWS;

    // ---- phase 0: stage W, spans, dinv slice; (layer 3) pool metadata ----
    for (int idx = t * 4; idx < DF * DF; idx += 512 * 4) {
        float4 w = *(const float4*)&W[idx];
        Ws[idx >> 6][(idx & 63) + 0] = w.x;
        Ws[idx >> 6][(idx & 63) + 1] = w.y;
        Ws[idx >> 6][(idx & 63) + 2] = w.z;
        Ws[idx >> 6][(idx & 63) + 3] = w.w;
    }
    if (t == 0) sh_e0 = offs[row0];
    if (t == 1) sh_e1 = offs[row0 + FB_ROWS];
    if (t < FB_ROWS) {
        int n = row0 + t;
        sh_dinv[t] = (n < N_NODES) ? dinv[n] : 0.f;
    }
    if (pool) {
        if (t < 4 * DF) plocal[t] = 0.f;
        if (t < FB_ROWS) {
            int n = row0 + t;
            sh_batch[t] = batch[n < N_NODES ? n : N_NODES - 1];
        }
    }

    const int wv = t >> 6;
    const int l  = t & 63;
    const int g  = l >> 4;      // edge lane-group 0..3
    const int q  = l & 15;      // feature quad 0..15

    // ---- phase 1a: self-loop init (plain stores, before any atomics) ----
    for (int ii = 0; ii < 8; ++ii) {
        int r = wv * 8 + ii;
        int n = row0 + r;
        if (l < 16) {
            float4 o = make_float4(0.f, 0.f, 0.f, 0.f);
            if (n < N_NODES) {
                float dc = dinv[n];
                float s  = dc * dc;
                float4 xv = *(const float4*)&h[n * DF + q * 4];
                o.x = s * xv.x; o.y = s * xv.y; o.z = s * xv.z; o.w = s * xv.w;
            }
            Xacc[r][q * 4 + 0] = o.x;
            Xacc[r][q * 4 + 1] = o.y;
            Xacc[r][q * 4 + 2] = o.z;
            Xacc[r][q * 4 + 3] = o.w;
        }
    }
    __syncthreads();

    // ---- phase 1b: stream this wave's edge slice ----
    const int e0 = sh_e0, e1 = sh_e1;
    const int cnt = e1 - e0;
    const int chunk = (cnt + 7) >> 3;        // per-wave slice
    const int wsrt = e0 + wv * chunk;
    int we = wsrt + chunk; if (we > e1) we = e1;

    const int base_ln = row0 & ((1 << RSH) - 1);
    int cur = -1;
    float ax = 0.f, ay = 0.f, az = 0.f, aw = 0.f;

#define FLUSH() do { float sd = sh_dinv[cur];                       \
        atomicAdd(&Xacc[cur][(q << 2) + 0], ax * sd);               \
        atomicAdd(&Xacc[cur][(q << 2) + 1], ay * sd);               \
        atomicAdd(&Xacc[cur][(q << 2) + 2], az * sd);               \
        atomicAdd(&Xacc[cur][(q << 2) + 3], aw * sd);               \
        ax = ay = az = aw = 0.f; } while (0)

    int e = wsrt + g;
    // unroll-2: 2 independent h-row chains in flight per lane (8 per wave)
    for (; e + 4 < we; e += 8) {
        unsigned p0 = epack[e];
        unsigned p1 = epack[e + 4];
        int r0 = (int)(p0 & 0xFFFFu);
        int r1 = (int)(p1 & 0xFFFFu);
        int c0 = (int)(p0 >> 16) - base_ln;
        int c1 = (int)(p1 >> 16) - base_ln;
        float w0 = dinv[r0];
        float w1 = dinv[r1];
        float4 v0 = *(const float4*)&h[(r0 << 6) + (q << 2)];
        float4 v1 = *(const float4*)&h[(r1 << 6) + (q << 2)];
        if (c0 != cur) { if (cur >= 0) FLUSH(); cur = c0; }
        ax += v0.x * w0; ay += v0.y * w0; az += v0.z * w0; aw += v0.w * w0;
        if (c1 != cur) { FLUSH(); cur = c1; }
        ax += v1.x * w1; ay += v1.y * w1; az += v1.z * w1; aw += v1.w * w1;
    }
    for (; e < we; e += 4) {
        unsigned p0 = epack[e];
        int r0 = (int)(p0 & 0xFFFFu);
        int c0 = (int)(p0 >> 16) - base_ln;
        float w0 = dinv[r0];
        float4 v0 = *(const float4*)&h[(r0 << 6) + (q << 2)];
        if (c0 != cur) { if (cur >= 0) FLUSH(); cur = c0; }
        ax += v0.x * w0; ay += v0.y * w0; az += v0.z * w0; aw += v0.w * w0;
    }
    if (cur >= 0) FLUSH();
#undef FLUSH
    __syncthreads();

    // ---- phase 2: GEMM, 4x2 register tile (node-major Xacc, b32 reads) ----
    const int i = (t & 15) * 4;   // node offset in tile
    const int j = (t >> 4) * 2;   // output col (0..62, even)
    float acc[4][2] = {};
    #pragma unroll 8
    for (int k = 0; k < DF; ++k) {
        float x0 = Xacc[i + 0][k];
        float x1 = Xacc[i + 1][k];
        float x2 = Xacc[i + 2][k];
        float x3 = Xacc[i + 3][k];
        float2 wvv = *(const float2*)&Ws[k][j];
        acc[0][0] += x0 * wvv.x; acc[0][1] += x0 * wvv.y;
        acc[1][0] += x1 * wvv.x; acc[1][1] += x1 * wvv.y;
        acc[2][0] += x2 * wvv.x; acc[2][1] += x2 * wvv.y;
        acc[3][0] += x3 * wvv.x; acc[3][1] += x3 * wvv.y;
    }
    const float bx = bias[j], by = bias[j + 1];

    if (!pool) {
        #pragma unroll
        for (int u = 0; u < 4; ++u) {
            int gr = row0 + i + u;
            if (gr < N_NODES) {
                float ox = acc[u][0] + bx;
                float oy = acc[u][1] + by;
                ox = ox > 0.f ? ox : 0.f;
                oy = oy > 0.f ? oy : 0.f;
                *(float2*)&out[gr * DF + j] = make_float2(ox, oy);
            }
        }
    } else {
        // layer-3 epilogue: relu then block-local mean-pool accumulation.
        const int g0 = sh_batch[0];
        const int span = sh_batch[FB_ROWS - 1] - g0 + 1;
        if (span <= 4) {
            #pragma unroll
            for (int u = 0; u < 4; ++u) {
                int gr = row0 + i + u;
                if (gr < N_NODES) {
                    float ox = acc[u][0] + bx;
                    float oy = acc[u][1] + by;
                    ox = ox > 0.f ? ox : 0.f;
                    oy = oy > 0.f ? oy : 0.f;
                    int gl = sh_batch[i + u] - g0;
                    atomicAdd(&plocal[gl * DF + j],     ox);
                    atomicAdd(&plocal[gl * DF + j + 1], oy);
                }
            }
            __syncthreads();
            for (int idx = t; idx < span * DF; idx += 512)
                atomicAdd(&pool[g0 * DF + idx], plocal[idx]);
        } else {
            // defensive fallback (sorted batch, ~781 nodes/graph: never hit)
            #pragma unroll
            for (int u = 0; u < 4; ++u) {
                int gr = row0 + i + u;
                if (gr < N_NODES) {
                    float ox = acc[u][0] + bx;
                    float oy = acc[u][1] + by;
                    ox = ox > 0.f ? ox : 0.f;
                    oy = oy > 0.f ? oy : 0.f;
                    int gg = sh_batch[i + u];
                    atomicAdd(&pool[gg * DF + j],     ox);
                    atomicAdd(&pool[gg * DF + j + 1], oy);
                }
            }
        }
    }
}

// ---------------- final divide; counts via binary search on sorted batch ----
__device__ __forceinline__ int lb(const int* a, int n, int key) {
    int lo = 0, hi = n;
    while (lo < hi) { int m = (lo + hi) >> 1; if (a[m] < key) lo = m + 1; else hi = m; }
    return lo;
}

__global__ void k_div(const float* __restrict__ pool, const int* __restrict__ batch,
                      float* __restrict__ out) {
    int idx = blockIdx.x * blockDim.x + threadIdx.x;
    if (idx < N_GRAPHS * DF) {
        int g = idx >> 6;
        int c = lb(batch, N_NODES, g + 1) - lb(batch, N_NODES, g);
        out[idx] = pool[idx] / fmaxf((float)c, 1.0f);
    }
}

// ---------------- launch ----------------

extern "C" void kernel_launch(void* const* d_in, const int* in_sizes, int n_in,
                              void* d_out, int out_size, void* d_ws, size_t ws_size,
                              hipStream_t stream) {
    const float* x     = (const float*)d_in[0];
    const int*   ei    = (const int*)d_in[1];      // [2, E] flat: row then col
    const int*   batch = (const int*)d_in[2];
    const float* W1    = (const float*)d_in[3];
    const float* b1    = (const float*)d_in[4];
    const float* W2    = (const float*)d_in[5];
    const float* b2    = (const float*)d_in[6];
    const float* W3    = (const float*)d_in[7];
    const float* b3    = (const float*)d_in[8];
    float* out = (float*)d_out;

    const int* row = ei;             // source
    const int* col = ei + N_EDGES;   // target (aggregation index)

    // workspace layout (4-byte elements)
    char* wsb = (char*)d_ws;
    float*    pool    = (float*)wsb;                     // N_GRAPHS*DF
    int*      H       = (int*)(pool + N_GRAPHS * DF);    // RPAD*ABLK (transposed)
    int*      O       = H + RPAD * ABLK;                 // RPAD*ABLK (transposed)
    int*      T       = O + RPAD * ABLK;                 // RPAD
    int*      offs    = T + RPAD;                        // NPAD
    unsigned* epack   = (unsigned*)(offs + NPAD);        // N_EDGES
    unsigned* staging = epack + N_EDGES;                 // N_EDGES
    float*    dinv    = (float*)(staging + N_EDGES);     // NPAD
    float*    bufA    = dinv + NPAD;                     // N_NODES*DF
    float*    bufB    = bufA + N_NODES * DF;             // N_NODES*DF

    const int nblk_F = (N_NODES + FB_ROWS - 1) / FB_ROWS;    // 782

    // CSR build: hist (also zeroes pool) -> per-region scan -> bin -> CSR
    k_hist<<<ABLK, 256, 0, stream>>>(col, H, pool);
    k_scanH<<<RPAD, 256, 0, stream>>>(H, O, T);
    k_bin<<<ABLK, 256, 0, stream>>>(row, col, O, T, staging);
    k_csr<<<NREG, 512, 0, stream>>>(staging, T, offs, dinv, epack);

    // fused layers: h = relu((A_hat h_prev) @ W + b)
    k_fused<<<nblk_F, 512, 0, stream>>>(offs, epack, dinv, x,    W1, b1, bufA,
                                        nullptr, nullptr);
    k_fused<<<nblk_F, 512, 0, stream>>>(offs, epack, dinv, bufA, W2, b2, bufB,
                                        nullptr, nullptr);
    // layer 3: no h write; outputs pooled directly (pool zeroed by k_hist)
    k_fused<<<nblk_F, 512, 0, stream>>>(offs, epack, dinv, bufB, W3, b3, nullptr,
                                        batch, pool);

    k_div<<<(N_GRAPHS * DF + 255) / 256, 256, 0, stream>>>(pool, batch, out);
}

// Round 4
// 258.527 us; speedup vs baseline: 1.8758x; 1.8758x over previous
//
#include <hip/hip_runtime.h>

#define N_NODES   50000
#define N_EDGES   800000
#define DF        64          // feature dim (D_IN == D_HID == 64)
#define N_GRAPHS  64
#define NPAD      50176       // 98*512, padded node count

// ---- two-level counting-sort CSR build (no global atomics, no write amp) ----
#define ABLK 200              // binning blocks
#define AEDG (N_EDGES/ABLK)   // 4000 edges per block
#define RSH  9                // 512 nodes per region
#define NREG 98               // 98*512 = 50176 >= N_NODES
#define RPAD 128              // padded region count
#define CAP  12288            // LDS image capacity per region (avg 8163)

// Pass A1: per-block region histogram -> H transposed [region][block]
// Block 0 also zeroes the pool buffer.
__global__ __launch_bounds__(256)
void k_hist(const int* __restrict__ col, int* __restrict__ H,
            float* __restrict__ pool) {
    __shared__ int h[RPAD];
    const int t = threadIdx.x, b = blockIdx.x;
    if (b == 0)
        for (int i = t; i < N_GRAPHS * DF; i += 256) pool[i] = 0.f;
    if (t < RPAD) h[t] = 0;
    __syncthreads();
    const int e0 = b * AEDG;
    for (int i = t; i < AEDG; i += 256)
        atomicAdd(&h[col[e0 + i] >> RSH], 1);
    __syncthreads();
    if (t < RPAD) H[t * ABLK + b] = h[t];
}

// Pass A2: one block PER REGION: exclusive scan of H[r][0..199] -> O, total -> T
__global__ __launch_bounds__(256)
void k_scanH(const int* __restrict__ H, int* __restrict__ O,
             int* __restrict__ T) {
    __shared__ int s[256];
    const int t = threadIdx.x, r = blockIdx.x;
    int v = (t < ABLK) ? H[r * ABLK + t] : 0;
    s[t] = v; __syncthreads();
    #pragma unroll
    for (int off = 1; off < 256; off <<= 1) {
        int x = (t >= off) ? s[t - off] : 0;
        __syncthreads();
        s[t] += x;
        __syncthreads();
    }
    if (t < ABLK) O[r * ABLK + t] = s[t] - v;   // exclusive, region-local
    if (t == 255) T[r] = s[255];
}

// Pass A3: scatter packed edges into region-sorted staging (block-local runs).
__global__ __launch_bounds__(256)
void k_bin(const int* __restrict__ row, const int* __restrict__ col,
           const int* __restrict__ O, const int* __restrict__ T,
           unsigned* __restrict__ staging) {
    __shared__ int cur[RPAD];
    __shared__ int rs[RPAD];
    const int t = threadIdx.x, b = blockIdx.x;
    int v = 0;
    if (t < RPAD) { v = T[t]; rs[t] = v; }
    __syncthreads();
    #pragma unroll
    for (int off = 1; off < RPAD; off <<= 1) {
        int x = 0;
        if (t < RPAD && t >= off) x = rs[t - off];
        __syncthreads();
        if (t < RPAD) rs[t] += x;
        __syncthreads();
    }
    if (t < RPAD) cur[t] = O[t * ABLK + b] + (rs[t] - v);   // + R[t]
    __syncthreads();
    const int e0 = b * AEDG;
    for (int i = t; i < AEDG; i += 256) {
        int c = col[e0 + i];
        int rr = row[e0 + i];
        int slot = atomicAdd(&cur[c >> RSH], 1);      // LDS atomic
        staging[slot] = ((unsigned)c << 16) | (unsigned)rr;
    }
}

// Pass B: one block per region -> offs, dinv, epack (all coalesced writes).
// epack[e] low 16 bits = source node id (N_NODES < 65536).
__global__ __launch_bounds__(512)
void k_csr(const unsigned* __restrict__ staging, const int* __restrict__ T,
           int* __restrict__ offs, float* __restrict__ dinv,
           unsigned* __restrict__ epack) {
    __shared__ int hist[512];
    __shared__ int cur[512];
    __shared__ unsigned img[CAP];
    __shared__ int rs[RPAD];
    __shared__ int sh_s0, sh_s1;
    const int t = threadIdx.x, r = blockIdx.x;
    int v = 0;
    if (t < RPAD) { v = T[t]; rs[t] = v; }
    __syncthreads();
    #pragma unroll
    for (int off = 1; off < RPAD; off <<= 1) {
        int x = 0;
        if (t < RPAD && t >= off) x = rs[t - off];
        __syncthreads();
        if (t < RPAD) rs[t] += x;
        __syncthreads();
    }
    if (t == r) { sh_s0 = rs[t] - v; sh_s1 = rs[t]; }
    hist[t] = 0;
    __syncthreads();
    const int s0 = sh_s0, s1 = sh_s1;
    for (int i = s0 + t; i < s1; i += 512) {
        int ln = (int)(staging[i] >> 16) - (r << RSH);
        atomicAdd(&hist[ln], 1);
    }
    __syncthreads();
    int myc = hist[t];
    #pragma unroll
    for (int off = 1; off < 512; off <<= 1) {         // inclusive scan
        int x = (t >= off) ? hist[t - off] : 0;
        __syncthreads();
        hist[t] += x;
        __syncthreads();
    }
    int excl = hist[t] - myc;
    int n = (r << RSH) + t;
    offs[n] = s0 + excl;                               // incl. sentinel nodes
    if (n < N_NODES) dinv[n] = rsqrtf((float)(myc + 1));
    cur[t] = excl;
    __syncthreads();
    for (int i = s0 + t; i < s1; i += 512) {
        unsigned p = staging[i];
        int ln = (int)(p >> 16) - (r << RSH);
        unsigned rr = p & 0xFFFFu;
        unsigned pk = rr | ((unsigned)ln << 16);
        int slot = atomicAdd(&cur[ln], 1);             // LDS atomic
        if (slot < CAP) img[slot] = pk;
        else           epack[s0 + slot] = pk;          // overflow fallback
    }
    __syncthreads();
    int cnt = s1 - s0; if (cnt > CAP) cnt = CAP;
    for (int j = t; j < cnt; j += 512) epack[s0 + j] = img[j];
}

// ---------------- fused gather + GEMM (+ pool epilogue), R2 structure --------
// Latency fix over R0:
//  (a) phase A stages (weight,src) for the block's contiguous edge span into
//      LDS (flat, parallel) -> hot loop has ONE global load (h-row), chain
//      depth 1 instead of offs->esrc->dinv/h (3).
//  (b) 4 nodes concurrent per wave (16 lanes each own a feature quad),
//      unroll-8 with predication -> up to 32 independent h-rows in flight per
//      wave AND no cross-lane reduce (each lane holds its quad's full sum).
// R3 fix: self-loop seed is dc*h (final write multiplies by dc -> dc^2*h);
// R2's dc*dc seed produced dc^3 (absmax 4.2e-3 fail).
#define FB_ROWS 64
#define LDX 68
#define ECAP 2048            // staged edges per block (avg span ~1030)

__global__ __launch_bounds__(512, 4)
void k_fused(const int* __restrict__ offs, const unsigned* __restrict__ epack,
             const float* __restrict__ dinv, const float* __restrict__ h,
             const float* __restrict__ W, const float* __restrict__ bias,
             float* __restrict__ out, const int* __restrict__ batch,
             float* __restrict__ pool) {
    __shared__ float  XsT[DF][LDX];     // 17.4 KB, transposed agg tile
    __shared__ float  Ws[DF][DF];       // 16 KB
    __shared__ float2 ew_l[ECAP];       // 16 KB: (.x = dinv[src], .y = src bits)
    __shared__ int    s_offs[FB_ROWS + 1];
    __shared__ float  sh_dinv[FB_ROWS];
    __shared__ float  plocal[4 * DF];   // block-local pool partials
    __shared__ int    sh_batch[FB_ROWS];

    const int t = threadIdx.x;
    const int row0 = blockIdx.x * FB_ROWS;

    // ---- phase 0: stage W, offs slice, dinv slice; (layer 3) pool meta ----
    for (int idx = t * 4; idx < DF * DF; idx += 512 * 4) {
        float4 w = *(const float4*)&W[idx];
        Ws[idx >> 6][(idx & 63) + 0] = w.x;
        Ws[idx >> 6][(idx & 63) + 1] = w.y;
        Ws[idx >> 6][(idx & 63) + 2] = w.z;
        Ws[idx >> 6][(idx & 63) + 3] = w.w;
    }
    if (t <= FB_ROWS) s_offs[t] = offs[row0 + t];
    if (t < FB_ROWS) {
        int n = row0 + t;
        sh_dinv[t] = (n < N_NODES) ? dinv[n] : 0.f;
    }
    if (pool) {
        if (t < 4 * DF) plocal[t] = 0.f;
        if (t < FB_ROWS) {
            int n = row0 + t;
            sh_batch[t] = batch[n < N_NODES ? n : N_NODES - 1];
        }
    }
    __syncthreads();

    // ---- phase A: stage (weight, src) for the block's edge span ----
    const int eb  = s_offs[0];
    const int cnt = s_offs[FB_ROWS] - eb;
    const int lim = cnt < ECAP ? cnt : ECAP;
    for (int i = t; i < lim; i += 512) {
        unsigned src = epack[eb + i] & 0xFFFFu;
        ew_l[i] = make_float2(dinv[src], __uint_as_float(src));
    }
    __syncthreads();

    // ---- phase 1: gather. wave = 4 node-groups x 16 feature lanes ----
    const int wv = t >> 6;
    const int l  = t & 63;
    const int ng = l >> 4;          // node sub-group 0..3
    const int q4 = (l & 15) << 2;   // feature offset 0..60

    for (int set = 0; set < 2; ++set) {
        const int r = (wv << 3) + (set << 2) + ng;
        const int n = row0 + r;
        const float dc = sh_dinv[r];               // 0 for padded nodes
        const unsigned hn = (n < N_NODES) ? (unsigned)n : 0u;

        float4 acc;
        {   // self-loop seed: dc * h[n]; final write scales by dc -> dc^2*h[n]
            float4 xv = *(const float4*)&h[(hn << 6) + q4];
            acc.x = dc * xv.x; acc.y = dc * xv.y;
            acc.z = dc * xv.z; acc.w = dc * xv.w;
        }

        int s        = s_offs[r]     - eb;
        const int s1 = s_offs[r + 1] - eb;
        while (s < s1) {                           // divergent across groups: ok
            unsigned srcs[8]; float wgts[8];
            #pragma unroll
            for (int k = 0; k < 8; ++k) {
                const int li = s + k;
                unsigned sr = hn; float wg = 0.f;
                if (li < s1) {
                    if (li < ECAP) {
                        float2 ew = ew_l[li];
                        wg = ew.x; sr = __float_as_uint(ew.y);
                    } else {                       // overflow fallback (rare)
                        sr = epack[eb + li] & 0xFFFFu;
                        wg = dinv[sr];
                    }
                }
                srcs[k] = sr; wgts[k] = wg;
            }
            float4 v[8];
            #pragma unroll
            for (int k = 0; k < 8; ++k)
                v[k] = *(const float4*)&h[(srcs[k] << 6) + q4];
            #pragma unroll
            for (int k = 0; k < 8; ++k) {
                acc.x += wgts[k] * v[k].x; acc.y += wgts[k] * v[k].y;
                acc.z += wgts[k] * v[k].z; acc.w += wgts[k] * v[k].w;
            }
            s += 8;
        }

        XsT[q4 + 0][r] = acc.x * dc;
        XsT[q4 + 1][r] = acc.y * dc;
        XsT[q4 + 2][r] = acc.z * dc;
        XsT[q4 + 3][r] = acc.w * dc;
    }
    __syncthreads();

    // ---- phase 2: GEMM, 4x2 register tile per thread (512 thr / 4096 out) ----
    const int i = (t & 15) * 4;   // row offset in tile
    const int j = (t >> 4) * 2;   // col offset (0..62, even)
    float acc[4][2] = {};
    #pragma unroll 8
    for (int k = 0; k < DF; ++k) {
        float4 xv = *(const float4*)&XsT[k][i];
        float2 wvv = *(const float2*)&Ws[k][j];
        acc[0][0] += xv.x * wvv.x; acc[0][1] += xv.x * wvv.y;
        acc[1][0] += xv.y * wvv.x; acc[1][1] += xv.y * wvv.y;
        acc[2][0] += xv.z * wvv.x; acc[2][1] += xv.z * wvv.y;
        acc[3][0] += xv.w * wvv.x; acc[3][1] += xv.w * wvv.y;
    }
    const float bx = bias[j], by = bias[j + 1];

    if (!pool) {
        #pragma unroll
        for (int u = 0; u < 4; ++u) {
            int gr = row0 + i + u;
            if (gr < N_NODES) {
                float ox = acc[u][0] + bx;
                float oy = acc[u][1] + by;
                ox = ox > 0.f ? ox : 0.f;
                oy = oy > 0.f ? oy : 0.f;
                *(float2*)&out[gr * DF + j] = make_float2(ox, oy);
            }
        }
    } else {
        // layer-3 epilogue: relu then block-local mean-pool accumulation.
        const int g0 = sh_batch[0];
        const int span = sh_batch[FB_ROWS - 1] - g0 + 1;
        if (span <= 4) {
            #pragma unroll
            for (int u = 0; u < 4; ++u) {
                int gr = row0 + i + u;
                if (gr < N_NODES) {
                    float ox = acc[u][0] + bx;
                    float oy = acc[u][1] + by;
                    ox = ox > 0.f ? ox : 0.f;
                    oy = oy > 0.f ? oy : 0.f;
                    int gl = sh_batch[i + u] - g0;
                    atomicAdd(&plocal[gl * DF + j],     ox);
                    atomicAdd(&plocal[gl * DF + j + 1], oy);
                }
            }
            __syncthreads();
            for (int idx = t; idx < span * DF; idx += 512)
                atomicAdd(&pool[g0 * DF + idx], plocal[idx]);
        } else {
            // defensive fallback (sorted batch, ~781 nodes/graph: never hit)
            #pragma unroll
            for (int u = 0; u < 4; ++u) {
                int gr = row0 + i + u;
                if (gr < N_NODES) {
                    float ox = acc[u][0] + bx;
                    float oy = acc[u][1] + by;
                    ox = ox > 0.f ? ox : 0.f;
                    oy = oy > 0.f ? oy : 0.f;
                    int gg = sh_batch[i + u];
                    atomicAdd(&pool[gg * DF + j],     ox);
                    atomicAdd(&pool[gg * DF + j + 1], oy);
                }
            }
        }
    }
}

// ---------------- final divide; counts via binary search on sorted batch ----
__device__ __forceinline__ int lb(const int* a, int n, int key) {
    int lo = 0, hi = n;
    while (lo < hi) { int m = (lo + hi) >> 1; if (a[m] < key) lo = m + 1; else hi = m; }
    return lo;
}

__global__ void k_div(const float* __restrict__ pool, const int* __restrict__ batch,
                      float* __restrict__ out) {
    int idx = blockIdx.x * blockDim.x + threadIdx.x;
    if (idx < N_GRAPHS * DF) {
        int g = idx >> 6;
        int c = lb(batch, N_NODES, g + 1) - lb(batch, N_NODES, g);
        out[idx] = pool[idx] / fmaxf((float)c, 1.0f);
    }
}

// ---------------- launch ----------------

extern "C" void kernel_launch(void* const* d_in, const int* in_sizes, int n_in,
                              void* d_out, int out_size, void* d_ws, size_t ws_size,
                              hipStream_t stream) {
    const float* x     = (const float*)d_in[0];
    const int*   ei    = (const int*)d_in[1];      // [2, E] flat: row then col
    const int*   batch = (const int*)d_in[2];
    const float* W1    = (const float*)d_in[3];
    const float* b1    = (const float*)d_in[4];
    const float* W2    = (const float*)d_in[5];
    const float* b2    = (const float*)d_in[6];
    const float* W3    = (const float*)d_in[7];
    const float* b3    = (const float*)d_in[8];
    float* out = (float*)d_out;

    const int* row = ei;             // source
    const int* col = ei + N_EDGES;   // target (aggregation index)

    // workspace layout (4-byte elements)
    char* wsb = (char*)d_ws;
    float*    pool    = (float*)wsb;                     // N_GRAPHS*DF
    int*      H       = (int*)(pool + N_GRAPHS * DF);    // RPAD*ABLK (transposed)
    int*      O       = H + RPAD * ABLK;                 // RPAD*ABLK (transposed)
    int*      T       = O + RPAD * ABLK;                 // RPAD
    int*      offs    = T + RPAD;                        // NPAD
    unsigned* epack   = (unsigned*)(offs + NPAD);        // N_EDGES
    unsigned* staging = epack + N_EDGES;                 // N_EDGES
    float*    dinv    = (float*)(staging + N_EDGES);     // NPAD
    float*    bufA    = dinv + NPAD;                     // N_NODES*DF
    float*    bufB    = bufA + N_NODES * DF;             // N_NODES*DF

    const int nblk_F = (N_NODES + FB_ROWS - 1) / FB_ROWS;    // 782

    // CSR build: hist (also zeroes pool) -> per-region scan -> bin -> CSR
    k_hist<<<ABLK, 256, 0, stream>>>(col, H, pool);
    k_scanH<<<RPAD, 256, 0, stream>>>(H, O, T);
    k_bin<<<ABLK, 256, 0, stream>>>(row, col, O, T, staging);
    k_csr<<<NREG, 512, 0, stream>>>(staging, T, offs, dinv, epack);

    // fused layers: h = relu((A_hat h_prev) @ W + b)
    k_fused<<<nblk_F, 512, 0, stream>>>(offs, epack, dinv, x,    W1, b1, bufA,
                                        nullptr, nullptr);
    k_fused<<<nblk_F, 512, 0, stream>>>(offs, epack, dinv, bufA, W2, b2, bufB,
                                        nullptr, nullptr);
    // layer 3: no h write; outputs pooled directly (pool zeroed by k_hist)
    k_fused<<<nblk_F, 512, 0, stream>>>(offs, epack, dinv, bufB, W3, b3, nullptr,
                                        batch, pool);

    k_div<<<(N_GRAPHS * DF + 255) / 256, 256, 0, stream>>>(pool, batch, out);
}

// Round 5
// 245.073 us; speedup vs baseline: 1.9787x; 1.0549x over previous
//
#include <hip/hip_runtime.h>

#define N_NODES   50000
#define N_EDGES   800000
#define DF        64          // feature dim (D_IN == D_HID == 64)
#define N_GRAPHS  64
#define NPAD      50176       // 98*512, padded node count

// ---- two-level counting-sort CSR build (no global atomics, no write amp) ----
#define ABLK 200              // binning blocks
#define AEDG (N_EDGES/ABLK)   // 4000 edges per block
#define RSH  9                // 512 nodes per region
#define NREG 98               // 98*512 = 50176 >= N_NODES
#define RPAD 128              // padded region count
#define CAP  12288            // LDS image capacity per region (avg 8163)

// Pass A1: per-block region histogram -> H transposed [region][block]
// Block 0 also zeroes the pool buffer.
__global__ __launch_bounds__(256)
void k_hist(const int* __restrict__ col, int* __restrict__ H,
            float* __restrict__ pool) {
    __shared__ int h[RPAD];
    const int t = threadIdx.x, b = blockIdx.x;
    if (b == 0)
        for (int i = t; i < N_GRAPHS * DF; i += 256) pool[i] = 0.f;
    if (t < RPAD) h[t] = 0;
    __syncthreads();
    const int e0 = b * AEDG;
    for (int i = t; i < AEDG; i += 256)
        atomicAdd(&h[col[e0 + i] >> RSH], 1);
    __syncthreads();
    if (t < RPAD) H[t * ABLK + b] = h[t];
}

// Pass A2: one block PER REGION: exclusive scan of H[r][0..199] -> O, total -> T
__global__ __launch_bounds__(256)
void k_scanH(const int* __restrict__ H, int* __restrict__ O,
             int* __restrict__ T) {
    __shared__ int s[256];
    const int t = threadIdx.x, r = blockIdx.x;
    int v = (t < ABLK) ? H[r * ABLK + t] : 0;
    s[t] = v; __syncthreads();
    #pragma unroll
    for (int off = 1; off < 256; off <<= 1) {
        int x = (t >= off) ? s[t - off] : 0;
        __syncthreads();
        s[t] += x;
        __syncthreads();
    }
    if (t < ABLK) O[r * ABLK + t] = s[t] - v;   // exclusive, region-local
    if (t == 255) T[r] = s[255];
}

// Pass A3: scatter packed edges into region-sorted staging (block-local runs).
__global__ __launch_bounds__(256)
void k_bin(const int* __restrict__ row, const int* __restrict__ col,
           const int* __restrict__ O, const int* __restrict__ T,
           unsigned* __restrict__ staging) {
    __shared__ int cur[RPAD];
    __shared__ int rs[RPAD];
    const int t = threadIdx.x, b = blockIdx.x;
    int v = 0;
    if (t < RPAD) { v = T[t]; rs[t] = v; }
    __syncthreads();
    #pragma unroll
    for (int off = 1; off < RPAD; off <<= 1) {
        int x = 0;
        if (t < RPAD && t >= off) x = rs[t - off];
        __syncthreads();
        if (t < RPAD) rs[t] += x;
        __syncthreads();
    }
    if (t < RPAD) cur[t] = O[t * ABLK + b] + (rs[t] - v);   // + R[t]
    __syncthreads();
    const int e0 = b * AEDG;
    for (int i = t; i < AEDG; i += 256) {
        int c = col[e0 + i];
        int rr = row[e0 + i];
        int slot = atomicAdd(&cur[c >> RSH], 1);      // LDS atomic
        staging[slot] = ((unsigned)c << 16) | (unsigned)rr;
    }
}

// Pass B: one block per region -> offs, dinv, epack (all coalesced writes).
// epack[e] low 16 bits = source node id (N_NODES < 65536).
__global__ __launch_bounds__(512)
void k_csr(const unsigned* __restrict__ staging, const int* __restrict__ T,
           int* __restrict__ offs, float* __restrict__ dinv,
           unsigned* __restrict__ epack) {
    __shared__ int hist[512];
    __shared__ int cur[512];
    __shared__ unsigned img[CAP];
    __shared__ int rs[RPAD];
    __shared__ int sh_s0, sh_s1;
    const int t = threadIdx.x, r = blockIdx.x;
    int v = 0;
    if (t < RPAD) { v = T[t]; rs[t] = v; }
    __syncthreads();
    #pragma unroll
    for (int off = 1; off < RPAD; off <<= 1) {
        int x = 0;
        if (t < RPAD && t >= off) x = rs[t - off];
        __syncthreads();
        if (t < RPAD) rs[t] += x;
        __syncthreads();
    }
    if (t == r) { sh_s0 = rs[t] - v; sh_s1 = rs[t]; }
    hist[t] = 0;
    __syncthreads();
    const int s0 = sh_s0, s1 = sh_s1;
    for (int i = s0 + t; i < s1; i += 512) {
        int ln = (int)(staging[i] >> 16) - (r << RSH);
        atomicAdd(&hist[ln], 1);
    }
    __syncthreads();
    int myc = hist[t];
    #pragma unroll
    for (int off = 1; off < 512; off <<= 1) {         // inclusive scan
        int x = (t >= off) ? hist[t - off] : 0;
        __syncthreads();
        hist[t] += x;
        __syncthreads();
    }
    int excl = hist[t] - myc;
    int n = (r << RSH) + t;
    offs[n] = s0 + excl;                               // incl. sentinel nodes
    if (n < N_NODES) dinv[n] = rsqrtf((float)(myc + 1));
    cur[t] = excl;
    __syncthreads();
    for (int i = s0 + t; i < s1; i += 512) {
        unsigned p = staging[i];
        int ln = (int)(p >> 16) - (r << RSH);
        unsigned rr = p & 0xFFFFu;
        unsigned pk = rr | ((unsigned)ln << 16);
        int slot = atomicAdd(&cur[ln], 1);             // LDS atomic
        if (slot < CAP) img[slot] = pk;
        else           epack[s0 + slot] = pk;          // overflow fallback
    }
    __syncthreads();
    int cnt = s1 - s0; if (cnt > CAP) cnt = CAP;
    for (int j = t; j < cnt; j += 512) epack[s0 + j] = img[j];
}

// ---- k_scale: hs = dinv (.) x  (row-wise prescale for layer 1) ----
__global__ __launch_bounds__(256)
void k_scale(const float* __restrict__ x, const float* __restrict__ dinv,
             float* __restrict__ hs) {
    int i = blockIdx.x * blockDim.x + threadIdx.x;     // float4 index
    if (i < N_NODES * DF / 4) {
        int n = (i * 4) >> 6;
        float s = dinv[n];
        float4 v = ((const float4*)x)[i];
        v.x *= s; v.y *= s; v.z *= s; v.w *= s;
        ((float4*)hs)[i] = v;
    }
}

// ---------------- fused gather + GEMM (+ pool epilogue), R5 structure --------
// R5: inputs are PRE-SCALED (hs = dinv (.) h), so the gather is a pure
// unweighted sum of hs[src] rows: no per-edge dinv lookup, no weight regs,
// no ew_l float2 staging (ushort src only, 4 KB). LDS ~39 KB -> 4 blocks/CU
// = 32 waves/CU; __launch_bounds__(512,8) caps VGPR at 64 for full residency.
// Epilogue of layers 1-2 writes the NEXT layer's prescaled input
// (hs_out = dinv * relu(o)); layer 3 pools raw relu(o).
#define FB_ROWS 64
#define LDX 68
#define ECAP 2048            // staged edges per block (avg span ~1030)

__global__ __launch_bounds__(512, 8)
void k_fused(const int* __restrict__ offs, const unsigned* __restrict__ epack,
             const float* __restrict__ dinv, const float* __restrict__ hs,
             const float* __restrict__ W, const float* __restrict__ bias,
             float* __restrict__ out, const int* __restrict__ batch,
             float* __restrict__ pool) {
    __shared__ float  XsT[DF][LDX];        // 17.4 KB, transposed agg tile
    __shared__ float  Ws[DF][DF];          // 16 KB
    __shared__ unsigned short es_l[ECAP];  // 4 KB: src ids
    __shared__ int    s_offs[FB_ROWS + 1];
    __shared__ float  plocal[4 * DF];      // block-local pool partials
    __shared__ int    sh_batch[FB_ROWS];

    const int t = threadIdx.x;
    const int row0 = blockIdx.x * FB_ROWS;

    // ---- phase 0: stage W, offs slice; (layer 3) pool meta ----
    for (int idx = t * 4; idx < DF * DF; idx += 512 * 4) {
        float4 w = *(const float4*)&W[idx];
        Ws[idx >> 6][(idx & 63) + 0] = w.x;
        Ws[idx >> 6][(idx & 63) + 1] = w.y;
        Ws[idx >> 6][(idx & 63) + 2] = w.z;
        Ws[idx >> 6][(idx & 63) + 3] = w.w;
    }
    if (t <= FB_ROWS) s_offs[t] = offs[row0 + t];
    if (pool) {
        if (t < 4 * DF) plocal[t] = 0.f;
        if (t < FB_ROWS) {
            int n = row0 + t;
            sh_batch[t] = batch[n < N_NODES ? n : N_NODES - 1];
        }
    }
    __syncthreads();

    // ---- phase A: stage src ids for the block's edge span ----
    const int eb  = s_offs[0];
    const int cnt = s_offs[FB_ROWS] - eb;
    const int lim = cnt < ECAP ? cnt : ECAP;
    for (int i = t; i < lim; i += 512)
        es_l[i] = (unsigned short)(epack[eb + i] & 0xFFFFu);
    __syncthreads();

    // ---- phase 1: gather. wave = 4 node-groups x 16 feature lanes ----
    const int wv = t >> 6;
    const int l  = t & 63;
    const int ng = l >> 4;          // node sub-group 0..3
    const int q4 = (l & 15) << 2;   // feature offset 0..60

    for (int set = 0; set < 2; ++set) {
        const int r = (wv << 3) + (set << 2) + ng;
        const int n = row0 + r;
        const float dc = (n < N_NODES) ? dinv[n] : 0.f;
        const unsigned hn = (n < N_NODES) ? (unsigned)n : 0u;

        // self-loop seed: hs[n] (= dinv*h); final write scales by dc -> dc^2*h
        float4 acc = *(const float4*)&hs[(hn << 6) + q4];

        int s        = s_offs[r]     - eb;
        const int s1 = s_offs[r + 1] - eb;
        while (s < s1) {                           // divergent across groups: ok
            unsigned srcs[8];
            #pragma unroll
            for (int k = 0; k < 8; ++k) {
                const int li = s + k;
                unsigned sr = hn;
                if (li < s1)
                    sr = (li < ECAP) ? (unsigned)es_l[li]
                                     : (epack[eb + li] & 0xFFFFu);
                // invalid lanes re-read own row with weight 0
                srcs[k] = (li < s1) ? sr : hn;
            }
            float4 v[8];
            #pragma unroll
            for (int k = 0; k < 8; ++k)
                v[k] = *(const float4*)&hs[(srcs[k] << 6) + q4];
            #pragma unroll
            for (int k = 0; k < 8; ++k) {
                const int li = s + k;
                const float m = (li < s1) ? 1.f : 0.f;
                acc.x += m * v[k].x; acc.y += m * v[k].y;
                acc.z += m * v[k].z; acc.w += m * v[k].w;
            }
            s += 8;
        }

        XsT[q4 + 0][r] = acc.x * dc;
        XsT[q4 + 1][r] = acc.y * dc;
        XsT[q4 + 2][r] = acc.z * dc;
        XsT[q4 + 3][r] = acc.w * dc;
    }
    __syncthreads();

    // ---- phase 2: GEMM, 4x2 register tile per thread (512 thr / 4096 out) ----
    const int i = (t & 15) * 4;   // row offset in tile
    const int j = (t >> 4) * 2;   // col offset (0..62, even)
    float acc[4][2] = {};
    #pragma unroll 8
    for (int k = 0; k < DF; ++k) {
        float4 xv = *(const float4*)&XsT[k][i];
        float2 wvv = *(const float2*)&Ws[k][j];
        acc[0][0] += xv.x * wvv.x; acc[0][1] += xv.x * wvv.y;
        acc[1][0] += xv.y * wvv.x; acc[1][1] += xv.y * wvv.y;
        acc[2][0] += xv.z * wvv.x; acc[2][1] += xv.z * wvv.y;
        acc[3][0] += xv.w * wvv.x; acc[3][1] += xv.w * wvv.y;
    }
    const float bx = bias[j], by = bias[j + 1];

    if (!pool) {
        // layers 1-2: write NEXT layer's prescaled input hs = dinv * relu(o)
        #pragma unroll
        for (int u = 0; u < 4; ++u) {
            int gr = row0 + i + u;
            if (gr < N_NODES) {
                float sc = dinv[gr];
                float ox = acc[u][0] + bx;
                float oy = acc[u][1] + by;
                ox = ox > 0.f ? ox : 0.f;
                oy = oy > 0.f ? oy : 0.f;
                *(float2*)&out[gr * DF + j] = make_float2(ox * sc, oy * sc);
            }
        }
    } else {
        // layer-3 epilogue: relu then block-local mean-pool accumulation.
        const int g0 = sh_batch[0];
        const int span = sh_batch[FB_ROWS - 1] - g0 + 1;
        if (span <= 4) {
            #pragma unroll
            for (int u = 0; u < 4; ++u) {
                int gr = row0 + i + u;
                if (gr < N_NODES) {
                    float ox = acc[u][0] + bx;
                    float oy = acc[u][1] + by;
                    ox = ox > 0.f ? ox : 0.f;
                    oy = oy > 0.f ? oy : 0.f;
                    int gl = sh_batch[i + u] - g0;
                    atomicAdd(&plocal[gl * DF + j],     ox);
                    atomicAdd(&plocal[gl * DF + j + 1], oy);
                }
            }
            __syncthreads();
            for (int idx = t; idx < span * DF; idx += 512)
                atomicAdd(&pool[g0 * DF + idx], plocal[idx]);
        } else {
            // defensive fallback (sorted batch, ~781 nodes/graph: never hit)
            #pragma unroll
            for (int u = 0; u < 4; ++u) {
                int gr = row0 + i + u;
                if (gr < N_NODES) {
                    float ox = acc[u][0] + bx;
                    float oy = acc[u][1] + by;
                    ox = ox > 0.f ? ox : 0.f;
                    oy = oy > 0.f ? oy : 0.f;
                    int gg = sh_batch[i + u];
                    atomicAdd(&pool[gg * DF + j],     ox);
                    atomicAdd(&pool[gg * DF + j + 1], oy);
                }
            }
        }
    }
}

// ---------------- final divide; counts via binary search on sorted batch ----
__device__ __forceinline__ int lb(const int* a, int n, int key) {
    int lo = 0, hi = n;
    while (lo < hi) { int m = (lo + hi) >> 1; if (a[m] < key) lo = m + 1; else hi = m; }
    return lo;
}

__global__ void k_div(const float* __restrict__ pool, const int* __restrict__ batch,
                      float* __restrict__ out) {
    int idx = blockIdx.x * blockDim.x + threadIdx.x;
    if (idx < N_GRAPHS * DF) {
        int g = idx >> 6;
        int c = lb(batch, N_NODES, g + 1) - lb(batch, N_NODES, g);
        out[idx] = pool[idx] / fmaxf((float)c, 1.0f);
    }
}

// ---------------- launch ----------------

extern "C" void kernel_launch(void* const* d_in, const int* in_sizes, int n_in,
                              void* d_out, int out_size, void* d_ws, size_t ws_size,
                              hipStream_t stream) {
    const float* x     = (const float*)d_in[0];
    const int*   ei    = (const int*)d_in[1];      // [2, E] flat: row then col
    const int*   batch = (const int*)d_in[2];
    const float* W1    = (const float*)d_in[3];
    const float* b1    = (const float*)d_in[4];
    const float* W2    = (const float*)d_in[5];
    const float* b2    = (const float*)d_in[6];
    const float* W3    = (const float*)d_in[7];
    const float* b3    = (const float*)d_in[8];
    float* out = (float*)d_out;

    const int* row = ei;             // source
    const int* col = ei + N_EDGES;   // target (aggregation index)

    // workspace layout (4-byte elements)
    char* wsb = (char*)d_ws;
    float*    pool    = (float*)wsb;                     // N_GRAPHS*DF
    int*      H       = (int*)(pool + N_GRAPHS * DF);    // RPAD*ABLK (transposed)
    int*      O       = H + RPAD * ABLK;                 // RPAD*ABLK (transposed)
    int*      T       = O + RPAD * ABLK;                 // RPAD
    int*      offs    = T + RPAD;                        // NPAD
    unsigned* epack   = (unsigned*)(offs + NPAD);        // N_EDGES
    unsigned* staging = epack + N_EDGES;                 // N_EDGES
    float*    dinv    = (float*)(staging + N_EDGES);     // NPAD
    float*    bufA    = dinv + NPAD;                     // N_NODES*DF
    float*    bufB    = bufA + N_NODES * DF;             // N_NODES*DF

    const int nblk_F = (N_NODES + FB_ROWS - 1) / FB_ROWS;    // 782
    const int nblk_S = (N_NODES * DF / 4 + 255) / 256;       // 3125

    // CSR build: hist (also zeroes pool) -> per-region scan -> bin -> CSR
    k_hist<<<ABLK, 256, 0, stream>>>(col, H, pool);
    k_scanH<<<RPAD, 256, 0, stream>>>(H, O, T);
    k_bin<<<ABLK, 256, 0, stream>>>(row, col, O, T, staging);
    k_csr<<<NREG, 512, 0, stream>>>(staging, T, offs, dinv, epack);

    // layer-1 prescale: bufB = dinv (.) x   (bufB is free until layer 2)
    k_scale<<<nblk_S, 256, 0, stream>>>(x, dinv, bufB);

    // fused layers: hs_next = dinv (.) relu((A_hat-sum of hs) @ W + b)
    k_fused<<<nblk_F, 512, 0, stream>>>(offs, epack, dinv, bufB, W1, b1, bufA,
                                        nullptr, nullptr);
    k_fused<<<nblk_F, 512, 0, stream>>>(offs, epack, dinv, bufA, W2, b2, bufB,
                                        nullptr, nullptr);
    // layer 3: no h write; outputs pooled directly (pool zeroed by k_hist)
    k_fused<<<nblk_F, 512, 0, stream>>>(offs, epack, dinv, bufB, W3, b3, nullptr,
                                        batch, pool);

    k_div<<<(N_GRAPHS * DF + 255) / 256, 256, 0, stream>>>(pool, batch, out);
}